// Round 3
// baseline (559.400 us; speedup 1.0000x reference)
//
#include <hip/hip_runtime.h>
#include <hip/hip_bf16.h>
#include <stdint.h>

#define TOKENS 8192
#define DIN 4096
#define DOUT 4096
#define RNK 16
#define LORA_SCALE 2.0f

typedef __attribute__((ext_vector_type(8))) __bf16 bf16x8;
typedef __attribute__((ext_vector_type(4))) float f32x4;

__device__ __forceinline__ unsigned short f2bf(float f) {
    union { float f; unsigned int u; } v; v.f = f;
    unsigned int u = v.u;
    unsigned int r = (u + 0x7fffu + ((u >> 16) & 1u)) >> 16;  // RNE
    return (unsigned short)r;
}

__device__ __forceinline__ void async_copy16(const void* g, void* l) {
    __builtin_amdgcn_global_load_lds(
        (const __attribute__((address_space(1))) void*)g,
        (__attribute__((address_space(3))) void*)l,
        16, 0, 0);
}

// ---------------- kernel 1: cast x (fp32) -> bf16 ----------------
__global__ void cast_x_kernel(const float4* __restrict__ x, ushort4* __restrict__ xb) {
    int i = blockIdx.x * blockDim.x + threadIdx.x;
    float4 v = x[i];
    ushort4 o;
    o.x = f2bf(v.x); o.y = f2bf(v.y); o.z = f2bf(v.z); o.w = f2bf(v.w);
    xb[i] = o;
}

// ---------------- kernel 2: W' = bf16(W + 2 * B @ A) ----------------
__global__ void fold_w_kernel(const float* __restrict__ W,
                              const float* __restrict__ lA,
                              const float* __restrict__ lB,
                              ushort* __restrict__ Wb) {
    int o  = blockIdx.y;
    int i0 = (blockIdx.x * blockDim.x + threadIdx.x) * 4;
    __shared__ float sB[RNK];
    if (threadIdx.x < RNK) sB[threadIdx.x] = lB[(size_t)o * RNK + threadIdx.x];
    __syncthreads();
    float4 w = *(const float4*)(W + (size_t)o * DIN + i0);
    float ax = 0.f, ay = 0.f, az = 0.f, aw = 0.f;
#pragma unroll
    for (int r = 0; r < RNK; r++) {
        float4 a = *(const float4*)(lA + (size_t)r * DIN + i0);
        float b = sB[r];
        ax += b * a.x; ay += b * a.y; az += b * a.z; aw += b * a.w;
    }
    ushort4 outv;
    outv.x = f2bf(w.x + LORA_SCALE * ax);
    outv.y = f2bf(w.y + LORA_SCALE * ay);
    outv.z = f2bf(w.z + LORA_SCALE * az);
    outv.w = f2bf(w.w + LORA_SCALE * aw);
    *(ushort4*)(Wb + (size_t)o * DIN + i0) = outv;
}

// ---------------- kernel 3: Y = Xb @ Wb^T + bias ----------------
// 256x256 tile, BK=32, 4-slot LDS ring (128 KiB), m201 phase discipline:
// per tile, two 16-MFMA phases, each
//   { ds_read frags ; stage 1 unit (2 gload_lds) ; s_barrier ;
//     lgkmcnt(0) ; setprio(1) ; 16 MFMA ; setprio(0) ; s_barrier }
// The double-barrier lockstep forces the good LDS/MFMA alternation between
// SIMD-mate waves (m196: the fine interleave is the lever); counted vmcnt(8)
// at tile boundaries only (never 0 mid-loop, m218).
//
// Ring safety: tile t reads slot t&3 only; writes issued in tile t target slot
// (t+3)&3 == (t-1)&3, whose last readers finished before the boundary barrier
// of tile t-1. Writes for slot s (issued in tile s-3) are landed by the
// boundary vmcnt(8) of tile s-1 (FIFO retirement, m135).
#define BM 256
#define BN 256
#define BK 32
#define NTILES (DIN / BK)      // 128
#define SLOT_U16 16384         // A 8192 + B 8192 ushorts = 32 KB
#define SLOT_BYTES 32768
#define B_OFF_BYTES 16384

__global__ __launch_bounds__(512, 2) void gemm_bias_kernel(
    const ushort* __restrict__ Xb, const ushort* __restrict__ Wb,
    const float* __restrict__ bias, float* __restrict__ Y) {

    __shared__ ushort smem[4 * SLOT_U16];   // 128 KiB ring

    const int tid  = threadIdx.x;
    const int lane = tid & 63;
    const int wave = tid >> 6;

    // XCD-bijective swizzle: 512 wgs, 8 XCDs, 64 contiguous tiles per XCD.
    const int bid  = blockIdx.x;
    const int sbid = (bid & 7) * 64 + (bid >> 3);
    const int m0 = (sbid >> 4) * BM;
    const int n0 = (sbid & 15) * BN;

    const int wm = (wave >> 2) * 128;       // 2 M-wave-groups
    const int wn = (wave & 3) * 64;         // 4 N-wave-groups

    // staging source addresses (inverse of the LDS chunk swizzle; m173 pattern)
    auto srcoff = [](int ci) -> size_t {
        const int L = ci >> 3, p = ci & 7;
        const int u = p ^ (L & 7);
        return (size_t)(2 * L + (u >> 2)) * DIN + (size_t)((u & 3) * 8);
    };
    const ushort* pA0 = Xb + (size_t)m0 * DIN + srcoff(tid);
    const ushort* pA1 = Xb + (size_t)m0 * DIN + srcoff(tid + 512);
    const ushort* pB0 = Wb + (size_t)n0 * DIN + srcoff(tid);
    const ushort* pB1 = Wb + (size_t)n0 * DIN + srcoff(tid + 512);

#define STAGE_A(slot) do { \
        ushort* d_ = smem + (slot) * SLOT_U16 + tid * 8; \
        async_copy16(pA0, d_); async_copy16(pA1, d_ + 4096); \
        pA0 += BK; pA1 += BK; } while (0)
#define STAGE_B(slot) do { \
        ushort* d_ = smem + (slot) * SLOT_U16 + 8192 + tid * 8; \
        async_copy16(pB0, d_); async_copy16(pB1, d_ + 4096); \
        pB0 += BK; pB1 += BK; } while (0)

    // fragment-read byte offsets (swizzle-aware), constant per lane
    const int lr = lane & 15, qq = lane >> 4;
    const int pp = (qq + 4 * (lr & 1)) ^ ((lr >> 1) & 7);
    const int offA = ((wm >> 1) + (lr >> 1)) * 128 + pp * 16;
    const int offB = B_OFF_BYTES + ((wn >> 1) + (lr >> 1)) * 128 + pp * 16;
    const char* smemc = (const char*)smem;

    f32x4 acc[8][4] = {};
    bf16x8 af0[4], af1[4], bfr[4];

    // prologue: stage tiles 0,1,2; wait for tile 0 (tiles 1,2 = 8 loads in flight)
    STAGE_A(0); STAGE_B(0);
    STAGE_A(1); STAGE_B(1);
    STAGE_A(2); STAGE_B(2);
    asm volatile("s_waitcnt vmcnt(8)" ::: "memory");
    __builtin_amdgcn_s_barrier();

#pragma unroll 1
    for (int t = 0; t < NTILES; ++t) {
        const char* sa = smemc + (size_t)(t & 3) * SLOT_BYTES;
        const int  stslot  = (t + 3) & 3;
        const bool doStage = (t + 3 < NTILES);

        // ---- phase 0: frags (A lower half + B), stage A, barrier, MFMA ----
#pragma unroll
        for (int f = 0; f < 4; f++) af0[f] = *(const bf16x8*)(sa + offA + f * 1024);
#pragma unroll
        for (int f = 0; f < 4; f++) bfr[f] = *(const bf16x8*)(sa + offB + f * 1024);
        if (doStage) STAGE_A(stslot);
        __builtin_amdgcn_s_barrier();
        asm volatile("s_waitcnt lgkmcnt(0)" ::: "memory");
        __builtin_amdgcn_s_setprio(1);
#pragma unroll
        for (int mf = 0; mf < 4; mf++)
#pragma unroll
            for (int nf = 0; nf < 4; nf++)
                acc[mf][nf] = __builtin_amdgcn_mfma_f32_16x16x32_bf16(
                    af0[mf], bfr[nf], acc[mf][nf], 0, 0, 0);
        __builtin_amdgcn_s_setprio(0);
        __builtin_amdgcn_s_barrier();

        // ---- phase 1: frags (A upper half), stage B, barrier, MFMA ----
#pragma unroll
        for (int f = 0; f < 4; f++) af1[f] = *(const bf16x8*)(sa + offA + (4 + f) * 1024);
        if (doStage) STAGE_B(stslot);
        __builtin_amdgcn_s_barrier();
        asm volatile("s_waitcnt lgkmcnt(0)" ::: "memory");
        __builtin_amdgcn_s_setprio(1);
#pragma unroll
        for (int mf = 0; mf < 4; mf++)
#pragma unroll
            for (int nf = 0; nf < 4; nf++)
                acc[4 + mf][nf] = __builtin_amdgcn_mfma_f32_16x16x32_bf16(
                    af1[mf], bfr[nf], acc[4 + mf][nf], 0, 0, 0);
        __builtin_amdgcn_s_setprio(0);

        // ---- boundary: counted vmcnt + barrier (steady: tiles t+2,t+3 in flight) ----
        if (t < NTILES - 3) {
            asm volatile("s_waitcnt vmcnt(8)" ::: "memory");
            __builtin_amdgcn_s_barrier();
        } else if (t == NTILES - 3) {
            asm volatile("s_waitcnt vmcnt(4)" ::: "memory");
            __builtin_amdgcn_s_barrier();
        } else if (t == NTILES - 2) {
            asm volatile("s_waitcnt vmcnt(0)" ::: "memory");
            __builtin_amdgcn_s_barrier();
        }
        // t == NTILES-1: no successor; fall through to epilogue
    }

    // epilogue: C/D layout col=lane&15, row=(lane>>4)*4+reg [m89/m91]
    const int col  = lane & 15;
    const int qrow = (lane >> 4) * 4;
#pragma unroll
    for (int nf = 0; nf < 4; nf++) {
        const int n = n0 + wn + nf * 16 + col;
        const float bv = bias[n];
#pragma unroll
        for (int mf = 0; mf < 8; mf++) {
            const int m = m0 + wm + mf * 16 + qrow;
            float* yp = Y + (size_t)m * DOUT + n;
            yp[0]                  = acc[mf][nf].x + bv;
            yp[(size_t)DOUT]       = acc[mf][nf].y + bv;
            yp[2 * (size_t)DOUT]   = acc[mf][nf].z + bv;
            yp[3 * (size_t)DOUT]   = acc[mf][nf].w + bv;
        }
    }
#undef STAGE_A
#undef STAGE_B
}

extern "C" void kernel_launch(void* const* d_in, const int* in_sizes, int n_in,
                              void* d_out, int out_size, void* d_ws, size_t ws_size,
                              hipStream_t stream) {
    const float* x    = (const float*)d_in[0];
    const float* W    = (const float*)d_in[1];
    const float* bias = (const float*)d_in[2];
    const float* lA   = (const float*)d_in[3];
    const float* lB   = (const float*)d_in[4];
    float* Y = (float*)d_out;

    ushort* xb = (ushort*)d_ws;                       // 64 MB
    ushort* wb = xb + (size_t)TOKENS * DIN;           // +32 MB

    cast_x_kernel<<<(TOKENS * DIN / 4) / 256, 256, 0, stream>>>(
        (const float4*)x, (ushort4*)xb);
    fold_w_kernel<<<dim3(DIN / (256 * 4), DOUT), 256, 0, stream>>>(W, lA, lB, wb);
    gemm_bias_kernel<<<dim3((TOKENS / BM) * (DOUT / BN)), 512, 0, stream>>>(
        xb, wb, bias, Y);
}

// Round 4
// 535.407 us; speedup vs baseline: 1.0448x; 1.0448x over previous
//
#include <hip/hip_runtime.h>
#include <hip/hip_bf16.h>
#include <stdint.h>

#define TOKENS 8192
#define DIN 4096
#define DOUT 4096
#define RNK 16
#define LORA_SCALE 2.0f

typedef __attribute__((ext_vector_type(8))) __bf16 bf16x8;
typedef __attribute__((ext_vector_type(4))) float f32x4;

__device__ __forceinline__ unsigned short f2bf(float f) {
    union { float f; unsigned int u; } v; v.f = f;
    unsigned int u = v.u;
    unsigned int r = (u + 0x7fffu + ((u >> 16) & 1u)) >> 16;  // RNE
    return (unsigned short)r;
}

__device__ __forceinline__ void async_copy16(const void* g, void* l) {
    __builtin_amdgcn_global_load_lds(
        (const __attribute__((address_space(1))) void*)g,
        (__attribute__((address_space(3))) void*)l,
        16, 0, 0);
}

// ---------------- kernel 1: cast x (fp32) -> bf16 ----------------
__global__ void cast_x_kernel(const float4* __restrict__ x, ushort4* __restrict__ xb) {
    int i = blockIdx.x * blockDim.x + threadIdx.x;
    float4 v = x[i];
    ushort4 o;
    o.x = f2bf(v.x); o.y = f2bf(v.y); o.z = f2bf(v.z); o.w = f2bf(v.w);
    xb[i] = o;
}

// ---------------- kernel 2: W' = bf16(W + 2 * B @ A) ----------------
__global__ void fold_w_kernel(const float* __restrict__ W,
                              const float* __restrict__ lA,
                              const float* __restrict__ lB,
                              ushort* __restrict__ Wb) {
    int o  = blockIdx.y;
    int i0 = (blockIdx.x * blockDim.x + threadIdx.x) * 4;
    __shared__ float sB[RNK];
    if (threadIdx.x < RNK) sB[threadIdx.x] = lB[(size_t)o * RNK + threadIdx.x];
    __syncthreads();
    float4 w = *(const float4*)(W + (size_t)o * DIN + i0);
    float ax = 0.f, ay = 0.f, az = 0.f, aw = 0.f;
#pragma unroll
    for (int r = 0; r < RNK; r++) {
        float4 a = *(const float4*)(lA + (size_t)r * DIN + i0);
        float b = sB[r];
        ax += b * a.x; ay += b * a.y; az += b * a.z; aw += b * a.w;
    }
    ushort4 outv;
    outv.x = f2bf(w.x + LORA_SCALE * ax);
    outv.y = f2bf(w.y + LORA_SCALE * ay);
    outv.z = f2bf(w.z + LORA_SCALE * az);
    outv.w = f2bf(w.w + LORA_SCALE * aw);
    *(ushort4*)(Wb + (size_t)o * DIN + i0) = outv;
}

// ---------------- kernel 3: Y = Xb @ Wb^T + bias ----------------
// Faithful port of the m201 256x256 8-phase template (1563 TF @4k verified):
// BK=64, LDS = 2 slots x 2 halves x (128 rows x 64 bf16) per operand = 128 KiB.
// Iteration = 2 K-tiles (slot0 phases P1-4, slot1 phases P5-8). Each phase:
//   { ds_read subtile (12/4/8/0 x b128) ; stage half-tiles ; s_barrier ;
//     lgkmcnt(0) ; sched_barrier(0) ; setprio(1) ; 16 MFMA (one C-quadrant
//     x K=64) ; setprio(0) ; s_barrier }
// Adjacent phases write DIFFERENT acc quadrants -> no inter-phase MFMA dep:
// next phase's reads+MFMAs issue while previous cluster drains the pipe.
// Stages target the slot NOT being read: B-halves of t+2 in P3 (slot0 B reads
// done at P2 close), A-halves in P4 (A reads done at P3 close); P7/P8 same for
// slot1/t+3. Boundary vmcnt(8) at P4/P8 only: outstanding = exactly this
// pair's 8 loads -> everything older (incl. next tile's data) landed [m135
// FIFO]. vmcnt(0) only when no stage was issued (tail iterations).
//
// LDS swizzle: rows are 128 B (= bank period); chunk (16 B) at position
// p = g ^ (row&7) for global chunk g [m214's +89% fix]. global_load_lds writes
// linearly, so the inverse permutation is applied to the per-lane GLOBAL
// source address [m173]. Read: each bank-quad gets uniform 8 hits per
// ds_read_b128 -> conflict-free.
#define BM 256
#define BN 256
#define BK 64
#define NT (DIN / BK)          // 64 K-tiles
#define AREG 0                 // ushort index of A region
#define BREG 32768             // ushort index of B region (64 KiB in)

__global__ __launch_bounds__(512, 2) void gemm_bias_kernel(
    const ushort* __restrict__ Xb, const ushort* __restrict__ Wb,
    const float* __restrict__ bias, float* __restrict__ Y) {

    __shared__ ushort smem[65536];   // 128 KiB

    const int tid  = threadIdx.x;
    const int lane = tid & 63;
    const int wave = tid >> 6;

    // XCD-bijective swizzle: 512 wgs, 8 XCDs, 64 contiguous tiles per XCD.
    const int bid  = blockIdx.x;
    const int sbid = (bid & 7) * 64 + (bid >> 3);
    const int m0 = (sbid >> 4) * BM;
    const int n0 = (sbid & 15) * BN;

    const int wm128 = (wave >> 2) * 128;    // wave's M offset (2 M-groups)
    const int wn64  = (wave & 3) * 64;      // wave's N offset (4 N-groups)
    const int hA  = wave >> 2;              // A half this wave reads
    const int hB  = wn64 >> 7;              // B half this wave reads
    const int nB0 = wn64 & 127;             // row offset inside B half (0/64)

    // ---- staging source (inverse-swizzled): thread tid covers chunk tid and
    // tid+512 of a 16 KB half-buffer. chunk ci: line L=ci>>3, pos p=ci&7,
    // global chunk u=p^(L&7); +512 adds 64 rows (same u since 64%8==0).
    const int rowL = tid >> 3;
    const int uu   = (tid & 7) ^ (rowL & 7);
    const size_t prebase = (size_t)rowL * DIN + (size_t)(uu * 8);
    const ushort* pA = Xb + (size_t)m0 * DIN + prebase;
    const ushort* pB = Wb + (size_t)n0 * DIN + prebase;

#define STAGE_H(reg, src, h, t) do { \
        ushort* d_ = smem + (reg) + ((((t) & 1) << 1) + (h)) * 8192 + tid * 8; \
        const ushort* s_ = (src) + (size_t)(h) * (128 * (size_t)DIN) + (size_t)(t) * 64; \
        async_copy16(s_, d_); \
        async_copy16(s_ + (size_t)64 * DIN, d_ + 4096); \
    } while (0)

    // ---- read-side lane offsets (swizzle-aware) ----
    const int lr = lane & 15, qq = lane >> 4;
    const int l0 = lr * 128 + ((qq ^ (lr & 7)) * 16);        // ksub 0
    const int l1 = lr * 128 + (((4 + qq) ^ (lr & 7)) * 16);  // ksub 1
    const char* smemc = (const char*)smem;
    const char* aS0 = smemc + (0 + hA) * 16384;
    const char* aS1 = smemc + (2 + hA) * 16384;
    const char* bS0 = smemc + 65536 + (0 + hB) * 16384 + nB0 * 128;
    const char* bS1 = smemc + 65536 + (2 + hB) * 16384 + nB0 * 128;

#define LD8(p) (*(const bf16x8*)(p))
#define BAR_LGKM do { \
        __builtin_amdgcn_s_barrier(); \
        asm volatile("s_waitcnt lgkmcnt(0)" ::: "memory"); \
        __builtin_amdgcn_sched_barrier(0); \
        __builtin_amdgcn_s_setprio(1); \
    } while (0)
#define CLOSE do { \
        __builtin_amdgcn_s_setprio(0); \
        __builtin_amdgcn_s_barrier(); \
    } while (0)
#define MFMA_Q(mo, no, A_, B_) do { \
        _Pragma("unroll") \
        for (int m_ = 0; m_ < 4; m_++) \
        _Pragma("unroll") \
        for (int n_ = 0; n_ < 2; n_++) \
        _Pragma("unroll") \
        for (int k_ = 0; k_ < 2; k_++) \
            acc[(mo) + m_][(no) + n_] = __builtin_amdgcn_mfma_f32_16x16x32_bf16( \
                A_[m_][k_], B_[n_][k_], acc[(mo) + m_][(no) + n_], 0, 0, 0); \
    } while (0)

    f32x4 acc[8][4] = {};
    bf16x8 aa[4][2], b0[2][2], b1[2][2];

    // ---- prologue: stage tiles 0 (slot0) and 1 (slot1); tile 0 landed ----
    STAGE_H(AREG, pA, 0, 0); STAGE_H(AREG, pA, 1, 0);
    STAGE_H(BREG, pB, 0, 0); STAGE_H(BREG, pB, 1, 0);
    STAGE_H(AREG, pA, 0, 1); STAGE_H(AREG, pA, 1, 1);
    STAGE_H(BREG, pB, 0, 1); STAGE_H(BREG, pB, 1, 1);
    asm volatile("s_waitcnt vmcnt(8)" ::: "memory");
    __builtin_amdgcn_s_barrier();

    // ---- one K-tile = 4 phases; quadrant order Q00,Q01,Q11,Q10 ----
#define KTILE(AS, BS, ts, doSt) do { \
        /* P1: read A-sub0 (8) + B-sub0 (4); MFMA Q00 */ \
        _Pragma("unroll") \
        for (int m_ = 0; m_ < 4; m_++) { \
            aa[m_][0] = LD8(AS + m_ * 2048 + l0); \
            aa[m_][1] = LD8(AS + m_ * 2048 + l1); } \
        _Pragma("unroll") \
        for (int n_ = 0; n_ < 2; n_++) { \
            b0[n_][0] = LD8(BS + n_ * 2048 + l0); \
            b0[n_][1] = LD8(BS + n_ * 2048 + l1); } \
        BAR_LGKM; MFMA_Q(0, 0, aa, b0); CLOSE; \
        /* P2: read B-sub1 (4); MFMA Q01 */ \
        _Pragma("unroll") \
        for (int n_ = 0; n_ < 2; n_++) { \
            b1[n_][0] = LD8(BS + (n_ + 2) * 2048 + l0); \
            b1[n_][1] = LD8(BS + (n_ + 2) * 2048 + l1); } \
        BAR_LGKM; MFMA_Q(0, 2, aa, b1); CLOSE; \
        /* P3: read A-sub1 (8); stage B-halves of tile ts; MFMA Q11 */ \
        _Pragma("unroll") \
        for (int m_ = 0; m_ < 4; m_++) { \
            aa[m_][0] = LD8(AS + (m_ + 4) * 2048 + l0); \
            aa[m_][1] = LD8(AS + (m_ + 4) * 2048 + l1); } \
        if (doSt) { STAGE_H(BREG, pB, 0, ts); STAGE_H(BREG, pB, 1, ts); } \
        BAR_LGKM; MFMA_Q(4, 2, aa, b1); CLOSE; \
        /* P4: stage A-halves of tile ts; MFMA Q10; boundary vmcnt */ \
        if (doSt) { STAGE_H(AREG, pA, 0, ts); STAGE_H(AREG, pA, 1, ts); } \
        BAR_LGKM; MFMA_Q(4, 0, aa, b0); \
        __builtin_amdgcn_s_setprio(0); \
        if (doSt) { asm volatile("s_waitcnt vmcnt(8)" ::: "memory"); } \
        else      { asm volatile("s_waitcnt vmcnt(0)" ::: "memory"); } \
        __builtin_amdgcn_s_barrier(); \
    } while (0)

#pragma unroll 1
    for (int it = 0; it < NT / 2; ++it) {
        const int t0 = 2 * it, t1 = 2 * it + 1;
        KTILE(aS0, bS0, t0 + 2, (t0 + 2 < NT));   // phases 1-4 (slot 0)
        KTILE(aS1, bS1, t1 + 2, (t1 + 2 < NT));   // phases 5-8 (slot 1)
    }

    // ---- epilogue: C/D layout col=lane&15, row=(lane>>4)*4+reg [m89/m91] ----
    const int col  = lane & 15;
    const int qrow = (lane >> 4) * 4;
#pragma unroll
    for (int nf = 0; nf < 4; nf++) {
        const int n = n0 + wn64 + nf * 16 + col;
        const float bv = bias[n];
#pragma unroll
        for (int mf = 0; mf < 8; mf++) {
            const int m = m0 + wm128 + mf * 16 + qrow;
            float* yp = Y + (size_t)m * DOUT + n;
            yp[0]                = acc[mf][nf].x + bv;
            yp[(size_t)DOUT]     = acc[mf][nf].y + bv;
            yp[2 * (size_t)DOUT] = acc[mf][nf].z + bv;
            yp[3 * (size_t)DOUT] = acc[mf][nf].w + bv;
        }
    }
#undef STAGE_H
#undef KTILE
#undef MFMA_Q
#undef BAR_LGKM
#undef CLOSE
#undef LD8
}

extern "C" void kernel_launch(void* const* d_in, const int* in_sizes, int n_in,
                              void* d_out, int out_size, void* d_ws, size_t ws_size,
                              hipStream_t stream) {
    const float* x    = (const float*)d_in[0];
    const float* W    = (const float*)d_in[1];
    const float* bias = (const float*)d_in[2];
    const float* lA   = (const float*)d_in[3];
    const float* lB   = (const float*)d_in[4];
    float* Y = (float*)d_out;

    ushort* xb = (ushort*)d_ws;                       // 64 MB
    ushort* wb = xb + (size_t)TOKENS * DIN;           // +32 MB

    cast_x_kernel<<<(TOKENS * DIN / 4) / 256, 256, 0, stream>>>(
        (const float4*)x, (ushort4*)xb);
    fold_w_kernel<<<dim3(DIN / (256 * 4), DOUT), 256, 0, stream>>>(W, lA, lB, wb);
    gemm_bias_kernel<<<dim3((TOKENS / BM) * (DOUT / BN)), 512, 0, stream>>>(
        xb, wb, bias, Y);
}